// Round 14
// baseline (1225.842 us; speedup 1.0000x reference)
//
#include <hip/hip_runtime.h>
#include <hip/hip_bf16.h>
#include <math.h>

#define L_SEQ 4096
#define B_SZ 4
#define D_MODEL 512
#define D_INNER 1024
#define DT_RANK 32
#define D_STATE 16
#define M_ROWS (B_SZ * L_SEQ)   // 16384
#define NC 64                    // chunks per sequence
#define CHK (L_SEQ / NC)         // 64 steps per chunk

typedef __hip_bfloat16 bf16;
typedef __bf16 bf16x8 __attribute__((ext_vector_type(8)));
typedef float f32x4 __attribute__((ext_vector_type(4)));
struct us8 { ushort4 a, b; };    // 16-byte chunk of 8 bf16 bit patterns

// ---- bf16 bit conversions -------------------------------------------------
__device__ __forceinline__ unsigned short f2us(float f) {
    union { bf16 h; unsigned short u; } t;
    t.h = __float2bfloat16(f);
    return t.u;
}
__device__ __forceinline__ float us2f(unsigned short u) {
    union { bf16 h; unsigned short u; } t;
    t.u = u;
    return __bfloat162float(t.h);
}

// ---- hardened transcendentals ---------------------------------------------
__device__ __forceinline__ float silu_f(float x) {
    const float xc = fminf(fmaxf(x, -60.0f), 60.0f);
    return x / (1.0f + __expf(-xc));
}
__device__ __forceinline__ float softplus_f(float x) {
    if (x > 20.0f) return x;
    if (x < -20.0f) return __expf(x);
    return log1pf(__expf(x));
}

// ---------------------------------------------------------------------------
// Fused multi-segment f32 -> bf16 conversion (one dispatch for many tensors).
// ---------------------------------------------------------------------------
struct CvtArgs {
    const float* src[9];
    unsigned short* dst[9];
    unsigned int vend[9];   // cumulative vec4 counts
    int nseg;
};
__global__ __launch_bounds__(256)
void cvt_multi(CvtArgs a)
{
    const unsigned int v = blockIdx.x * 256 + threadIdx.x;
    if (v >= a.vend[a.nseg - 1]) return;
    int s = 0;
    unsigned int vstart = 0;
    while (v >= a.vend[s]) { vstart = a.vend[s]; ++s; }
    const size_t lv = (size_t)(v - vstart) * 4;
    const float4 f = *(const float4*)(a.src[s] + lv);
    ushort4 o;
    o.x = f2us(f.x); o.y = f2us(f.y); o.z = f2us(f.z); o.w = f2us(f.w);
    *(ushort4*)(a.dst[s] + lv) = o;
}

// ---------------------------------------------------------------------------
// MFMA bf16 "NT" GEMM v2: C[m,n] = sum_k A[m,k]*W[n,k], f32 accumulate.
// Staging via global_load_lds (16B DMA) into XOR-swizzled LDS.
// SWZ=1: XCD-chunked bijective blockIdx remap -- ONLY for the big in-proj
// GEMMs (A re-read x16 across col-blocks; per-XCD working set -> L2-sized).
// Round-5 lesson: blanket swizzle tripled the dtv GEMM (167.9 vs <=71 us),
// so it is opt-in per instantiation.
// GATED==1: A element = A*silu(A2), staged by VALU (same swizzle).
// EPI: 0 none; 1 softplus(acc+bias[n]); 2 dual write f32 C + bf16 C2 (n<32).
// CT : 0 C bf16, 1 C f32. Block 256 = 4 waves, wave tile (WY*16)x(WX*16).
// ---------------------------------------------------------------------------
template<int BM, int BN, int BK, int WY, int WX, int GATED, int EPI, int CT, int SWZ>
__global__ __launch_bounds__(256)
void gemm_mfma(const unsigned short* __restrict__ A,
               const unsigned short* __restrict__ A2,
               const unsigned short* __restrict__ W,
               const float* __restrict__ bias,
               void* __restrict__ Cp, unsigned short* __restrict__ C2p,
               int K, int lda, int ldb, int ldc)
{
    constexpr int CPR = BK / 8;        // 16B chunks per LDS row
    constexpr int SWM = CPR - 1;
    constexpr int RPW = 64 / CPR;      // rows per wave per DMA pass
    constexpr int NPA = BM / (4 * RPW);
    constexpr int NPB = BN / (4 * RPW);
    constexpr int WGX = BN / (WX * 16);
    static_assert(WGX * (BM / (WY * 16)) == 4, "4 waves");
    __shared__ unsigned short As[BM * BK];
    __shared__ unsigned short Bs[BN * BK];

    const int tid  = threadIdx.x;
    const int lane = tid & 63;
    const int wave = tid >> 6;
    const int wx = wave % WGX, wy = wave / WGX;
    const int l15 = lane & 15, quad = lane >> 4;

    int bid = blockIdx.y * gridDim.x + blockIdx.x;
    if (SWZ) {
        const int nwg = gridDim.x * gridDim.y;
        if ((nwg & 7) == 0) {
            const int cpx = nwg >> 3;
            bid = (bid & 7) * cpx + (bid >> 3);
        }
    }
    const int bxi = bid % gridDim.x;
    const int byi = bid / gridDim.x;
    const long row0 = (long)byi * BM;
    const long col0 = (long)bxi * BN;

    // DMA lane mapping: lane -> (row-in-pass, swizzled source chunk)
    const int rin = lane / CPR;
    const int gc  = (lane % CPR) ^ (rin & SWM);

    f32x4 acc[WY][WX];
#pragma unroll
    for (int i = 0; i < WY; ++i)
#pragma unroll
        for (int j = 0; j < WX; ++j) acc[i][j] = (f32x4){0.f, 0.f, 0.f, 0.f};

    for (int k0 = 0; k0 < K; k0 += BK) {
        if (GATED == 0) {
#pragma unroll
            for (int p = 0; p < NPA; ++p) {
                const int rb = (p * 4 + wave) * RPW;
                const unsigned short* gp = A + (row0 + rb + rin) * (long)lda + k0 + gc * 8;
                const int lb = __builtin_amdgcn_readfirstlane(rb * BK);
                __builtin_amdgcn_global_load_lds(
                    (const __attribute__((address_space(1))) void*)gp,
                    (__attribute__((address_space(3))) void*)(As + lb), 16, 0, 0);
            }
        } else {
#pragma unroll
            for (int v = 0; v < BM * BK / 2048; ++v) {
                const int e = (v * 256 + tid) * 8;
                const int r = e / BK, c = (e % BK) / 8;
                const long off = (row0 + r) * (long)lda + k0 + c * 8;
                const us8 ta = *(const us8*)(A + off);
                const us8 tg = *(const us8*)(A2 + off);
                us8 t;
                t.a.x = f2us(us2f(ta.a.x) * silu_f(us2f(tg.a.x)));
                t.a.y = f2us(us2f(ta.a.y) * silu_f(us2f(tg.a.y)));
                t.a.z = f2us(us2f(ta.a.z) * silu_f(us2f(tg.a.z)));
                t.a.w = f2us(us2f(ta.a.w) * silu_f(us2f(tg.a.w)));
                t.b.x = f2us(us2f(ta.b.x) * silu_f(us2f(tg.b.x)));
                t.b.y = f2us(us2f(ta.b.y) * silu_f(us2f(tg.b.y)));
                t.b.z = f2us(us2f(ta.b.z) * silu_f(us2f(tg.b.z)));
                t.b.w = f2us(us2f(ta.b.w) * silu_f(us2f(tg.b.w)));
                *(us8*)&As[r * BK + ((c ^ (r & SWM)) * 8)] = t;
            }
        }
#pragma unroll
        for (int p = 0; p < NPB; ++p) {
            const int rb = (p * 4 + wave) * RPW;
            const unsigned short* gp = W + (col0 + rb + rin) * (long)ldb + k0 + gc * 8;
            const int lb = __builtin_amdgcn_readfirstlane(rb * BK);
            __builtin_amdgcn_global_load_lds(
                (const __attribute__((address_space(1))) void*)gp,
                (__attribute__((address_space(3))) void*)(Bs + lb), 16, 0, 0);
        }
        __syncthreads();   // drains vmcnt (DMA) + lgkmcnt before LDS reads

#pragma unroll
        for (int kk = 0; kk < BK / 32; ++kk) {
            bf16x8 aF[WY], bF[WX];
#pragma unroll
            for (int i = 0; i < WY; ++i) {
                const int r  = wy * WY * 16 + i * 16 + l15;
                const int kc = (kk * 4 + quad) ^ (r & SWM);
                aF[i] = *(const bf16x8*)&As[r * BK + kc * 8];
            }
#pragma unroll
            for (int j = 0; j < WX; ++j) {
                const int r  = wx * WX * 16 + j * 16 + l15;
                const int kc = (kk * 4 + quad) ^ (r & SWM);
                bF[j] = *(const bf16x8*)&Bs[r * BK + kc * 8];
            }
#pragma unroll
            for (int i = 0; i < WY; ++i)
#pragma unroll
                for (int j = 0; j < WX; ++j)
                    acc[i][j] = __builtin_amdgcn_mfma_f32_16x16x32_bf16(
                        aF[i], bF[j], acc[i][j], 0, 0, 0);
        }
        __syncthreads();
    }

    // ---- epilogue: lane holds rows quad*4+r, col l15 of each 16x16 tile ----
#pragma unroll
    for (int i = 0; i < WY; ++i)
#pragma unroll
        for (int j = 0; j < WX; ++j) {
            const long mb = row0 + wy * WY * 16 + i * 16 + quad * 4;
            const long n  = col0 + wx * WX * 16 + j * 16 + l15;
            const float bv = (EPI == 1) ? bias[n] : 0.0f;
#pragma unroll
            for (int r = 0; r < 4; ++r) {
                float val = acc[i][j][r];
                if (EPI == 1) val = softplus_f(val + bv);
                const long off = (mb + r) * (long)ldc + n;
                if (CT == 0) ((unsigned short*)Cp)[off] = f2us(val);
                else         ((float*)Cp)[off] = val;
                if (EPI == 2 && n < DT_RANK) C2p[(mb + r) * DT_RANK + n] = f2us(val);
            }
        }
}

// ---------------------------------------------------------------------------
// Depthwise causal conv1d (k=4) + bias + SiLU, 8 d-elements per thread.
// ---------------------------------------------------------------------------
__global__ __launch_bounds__(256)
void conv_silu8(const unsigned short* __restrict__ xz, const float* __restrict__ w,
                const float* __restrict__ bias, unsigned short* __restrict__ xb, int rev)
{
    const int idx = blockIdx.x * 256 + threadIdx.x;   // over M_ROWS * 128
    const int g = idx & 127;
    const int m = idx >> 7;
    const int b = m >> 12;
    const int t = m & (L_SEQ - 1);
    const int d = g * 8;

    float s[8];
    {
        const float4 b0 = *(const float4*)(bias + d);
        const float4 b1 = *(const float4*)(bias + d + 4);
        s[0] = b0.x; s[1] = b0.y; s[2] = b0.z; s[3] = b0.w;
        s[4] = b1.x; s[5] = b1.y; s[6] = b1.z; s[7] = b1.w;
    }
    float4 wv[8];
#pragma unroll
    for (int j = 0; j < 8; ++j) wv[j] = *(const float4*)(w + (d + j) * 4);

    const unsigned short* xbase = xz + (size_t)b * L_SEQ * 2048 + d;
#pragma unroll
    for (int k = 0; k < 4; ++k) {
        const int src = t - 3 + k;
        if (src >= 0) {
            const int sm = rev ? (L_SEQ - 1 - src) : src;
            const us8 xv = *(const us8*)(xbase + (size_t)sm * 2048);
            const float tap[8] = {us2f(xv.a.x), us2f(xv.a.y), us2f(xv.a.z), us2f(xv.a.w),
                                  us2f(xv.b.x), us2f(xv.b.y), us2f(xv.b.z), us2f(xv.b.w)};
#pragma unroll
            for (int j = 0; j < 8; ++j) {
                const float wk = (k == 0) ? wv[j].x : (k == 1) ? wv[j].y
                               : (k == 2) ? wv[j].z : wv[j].w;
                s[j] = fmaf(wk, tap[j], s[j]);
            }
        }
    }
    us8 o;
    o.a.x = f2us(silu_f(s[0])); o.a.y = f2us(silu_f(s[1]));
    o.a.z = f2us(silu_f(s[2])); o.a.w = f2us(silu_f(s[3]));
    o.b.x = f2us(silu_f(s[4])); o.b.y = f2us(silu_f(s[5]));
    o.b.z = f2us(silu_f(s[6])); o.b.w = f2us(silu_f(s[7]));
    *(us8*)(xb + (size_t)m * 1024 + d) = o;
}

// ---------------------------------------------------------------------------
// A-structure probe + half-tree powers (bit-identical to verified full tree).
// ---------------------------------------------------------------------------
__device__ __forceinline__ bool a_struct_fast(const float* __restrict__ Alog,
                                              int d, float& A0)
{
    A0 = -__expf(Alog[d * 16]);
    bool fast = true;
#pragma unroll
    for (int n = 1; n < 16; ++n) {
        const float an = -__expf(Alog[d * 16 + n]);
        const float tg = (float)(n + 1) * A0;
        fast = fast && (fabsf(an - tg) <= 1e-5f * fabsf(tg));
    }
    return fast;
}
// Powers p1..p8 (same tree shape as the verified pow_tree16) then
// w[k] = wb * p_{k+1}, wb = p8 for the upper n-half, 1.0 for the lower
// (1.0*x is exact, so lower-half values are bit-identical to before).
__device__ __forceinline__ void pow_half8(float e1, float wb_sel, float w[8])
{
    const float p1 = e1;
    const float p2 = p1 * p1, p3 = p2 * p1, p4 = p2 * p2;
    const float p5 = p4 * p1, p6 = p4 * p2, p7 = p4 * p3, p8 = p4 * p4;
    const float wb = wb_sel ? p8 : 1.0f;
    w[0] = wb * p1; w[1] = wb * p2; w[2] = wb * p3; w[3] = wb * p4;
    w[4] = wb * p5; w[5] = wb * p6; w[6] = wb * p7; w[7] = wb * p8;
}

// ---------------------------------------------------------------------------
// Chunked selective scan, phase A. LANE-PAIR N-SPLIT (round 11 lesson:
// occupancy is capped by TOTAL threads, not block geometry -- 262144 threads
// = 50% of chip; block-size splits are no-ops). Thread (d, nh) owns 8 of the
// 16 states: tid = 2*dlocal + nh, d = blockIdx.y*512 + (tid>>1). 524288
// threads = 32 waves/CU (100% cap); per-thread serial work halves.
// ---------------------------------------------------------------------------
__global__ __launch_bounds__(1024, 8)
void scan_a(const unsigned short* __restrict__ dtq, const unsigned short* __restrict__ xq,
            const float* __restrict__ dbl, const float* __restrict__ Alog,
            float* __restrict__ hF, float* __restrict__ Ssum)
{
    const int tid = threadIdx.x;
    const int nh  = tid & 1;
    const int d   = blockIdx.y * 512 + (tid >> 1);
    const int nb  = nh * 8;
    const int c = blockIdx.x;
    const int b = blockIdx.z;

    __shared__ float Bsh[CHK][16];
    Bsh[tid >> 4][tid & 15] =
        dbl[((size_t)b * L_SEQ + c * CHK + (tid >> 4)) * 64 + DT_RANK + (tid & 15)];
    __syncthreads();

    float A0;
    const bool fast = a_struct_fast(Alog, d, A0);

    float h[8];
#pragma unroll
    for (int k = 0; k < 8; ++k) h[k] = 0.0f;
    float S = 0.0f;

    const size_t base = ((size_t)b * L_SEQ + c * CHK) * 1024 + d;
    const unsigned short* dtp = dtq + base;
    const unsigned short* xp  = xq + base;

    if (fast) {
        unsigned short bd[4], bx[4];
#pragma unroll
        for (int i = 0; i < 4; ++i) {
            bd[i] = dtp[(size_t)i * 1024];
            bx[i] = xp[(size_t)i * 1024];
        }
        for (int t0 = 0; t0 < CHK; t0 += 4) {
            unsigned short nd[4], nx[4];
            const bool pf = (t0 + 4 < CHK);
            if (pf) {
#pragma unroll
                for (int i = 0; i < 4; ++i) {
                    nd[i] = dtp[(size_t)(t0 + 4 + i) * 1024];
                    nx[i] = xp[(size_t)(t0 + 4 + i) * 1024];
                }
            }
#pragma unroll
            for (int i = 0; i < 4; ++i) {
                const float dt = us2f(bd[i]);
                const float xv = us2f(bx[i]);
                S += dt;
                const float dtx = dt * xv;
                float w[8];
                pow_half8(__expf(dt * A0), (float)nh, w);
#pragma unroll
                for (int k = 0; k < 8; ++k)
                    h[k] = fmaf(w[k], h[k], dtx * Bsh[t0 + i][nb + k]);
            }
            if (pf) {
#pragma unroll
                for (int i = 0; i < 4; ++i) { bd[i] = nd[i]; bx[i] = nx[i]; }
            }
        }
    } else {
        float Acoef[8];
#pragma unroll
        for (int k = 0; k < 8; ++k) Acoef[k] = -__expf(Alog[d * 16 + nb + k]);
        unsigned short vd = dtp[0], vx = xp[0];
        for (int t = 0; t < CHK; ++t) {
            unsigned short vd2 = 0, vx2 = 0;
            if (t + 1 < CHK) {
                vd2 = dtp[(size_t)(t + 1) * 1024];
                vx2 = xp[(size_t)(t + 1) * 1024];
            }
            const float dt = us2f(vd);
            const float xv = us2f(vx);
            S += dt;
            const float dtx = dt * xv;
#pragma unroll
            for (int k = 0; k < 8; ++k)
                h[k] = fmaf(__expf(dt * Acoef[k]), h[k], dtx * Bsh[t][nb + k]);
            vd = vd2; vx = vx2;
        }
    }

    float* hp = hF + ((((size_t)(b * NC + c) * 1024 + d) << 4) + nb);
#pragma unroll
    for (int k = 0; k < 8; ++k) hp[k] = h[k];
    if (nh == 0) Ssum[(size_t)(b * NC + c) * 1024 + d] = S;
}

// ---------------------------------------------------------------------------
// Phase B: sequential combine over chunks.
// ---------------------------------------------------------------------------
__global__ __launch_bounds__(256)
void scan_b(float* __restrict__ hF, const float* __restrict__ Ssum,
            const float* __restrict__ Alog)
{
    const int idx = blockIdx.x * 256 + threadIdx.x;   // B*D*16
    const int n  = idx & 15;
    const int dn = idx >> 4;
    const int d  = dn & (D_INNER - 1);
    const int b  = dn >> 10;

    const float Acoef = -__expf(Alog[d * 16 + n]);
    float H = 0.0f;
    for (int c = 0; c < NC; ++c) {
        const size_t base = (size_t)(b * NC + c) * 1024 + d;
        const float S = Ssum[base];
        float* hp = hF + (base << 4) + n;
        const float hOld = *hp;
        *hp = H;
        H = fmaf(__expf(Acoef * S), H, hOld);
    }
}

// ---------------------------------------------------------------------------
// Phase C: re-run chunk from true h_init; fused D*x + silu(z) gate; rev maps
// back to original time order; acc=1 accumulates; gate!=nullptr multiplies
// silu(gate). LANE-PAIR N-SPLIT (see scan_a): y combined via __shfl_xor(y,1)
// (partners are adjacent lanes, always in-wave); even lane stores.
// ---------------------------------------------------------------------------
__global__ __launch_bounds__(1024, 8)
void scan_c(const unsigned short* __restrict__ dtq, const unsigned short* __restrict__ xq,
            const float* __restrict__ dbl, const float* __restrict__ hF,
            const float* __restrict__ Alog, const float* __restrict__ Dp,
            const unsigned short* __restrict__ xz, unsigned short* __restrict__ yout,
            const unsigned short* __restrict__ gate, int rev, int acc)
{
    const int tid = threadIdx.x;
    const int nh  = tid & 1;
    const int d   = blockIdx.y * 512 + (tid >> 1);
    const int nb  = nh * 8;
    const int c = blockIdx.x;
    const int b = blockIdx.z;

    __shared__ float Bsh[CHK][16];
    __shared__ float Csh[CHK][16];
    {
        const size_t rb = ((size_t)b * L_SEQ + c * CHK + (tid >> 4)) * 64;
        Bsh[tid >> 4][tid & 15] = dbl[rb + DT_RANK + (tid & 15)];
        Csh[tid >> 4][tid & 15] = dbl[rb + DT_RANK + D_STATE + (tid & 15)];
    }
    __syncthreads();

    float A0;
    const bool fast = a_struct_fast(Alog, d, A0);
    const float Dd = Dp[d];

    float h[8];
    {
        const float* hp = hF + ((((size_t)(b * NC + c) * 1024 + d) << 4) + nb);
#pragma unroll
        for (int k = 0; k < 8; ++k) h[k] = hp[k];
    }

    const size_t base = ((size_t)b * L_SEQ + c * CHK) * 1024 + d;
    const unsigned short* dtp = dtq + base;
    const unsigned short* xp  = xq + base;
    const unsigned short* z_base = xz + (size_t)b * L_SEQ * 2048 + D_INNER + d;
    const unsigned short* g_base = gate ? gate + (size_t)b * L_SEQ * D_INNER + d : nullptr;
    unsigned short* y_base = yout + (size_t)b * L_SEQ * D_INNER + d;

    if (fast) {
        unsigned short bd[4], bx[4], bz[4], bg[4];
#pragma unroll
        for (int i = 0; i < 4; ++i) {
            bd[i] = dtp[(size_t)i * 1024];
            bx[i] = xp[(size_t)i * 1024];
            const int tg = c * CHK + i;
            const int tm = rev ? (L_SEQ - 1 - tg) : tg;
            bz[i] = z_base[(size_t)tm * 2048];
            bg[i] = g_base ? g_base[(size_t)tm * D_INNER] : (unsigned short)0;
        }
        for (int t0 = 0; t0 < CHK; t0 += 4) {
            unsigned short nd[4], nx[4], nz[4], ng[4];
            const bool pf = (t0 + 4 < CHK);
            if (pf) {
#pragma unroll
                for (int i = 0; i < 4; ++i) {
                    nd[i] = dtp[(size_t)(t0 + 4 + i) * 1024];
                    nx[i] = xp[(size_t)(t0 + 4 + i) * 1024];
                    const int tg = c * CHK + t0 + 4 + i;
                    const int tm = rev ? (L_SEQ - 1 - tg) : tg;
                    nz[i] = z_base[(size_t)tm * 2048];
                    ng[i] = g_base ? g_base[(size_t)tm * D_INNER] : (unsigned short)0;
                }
            }
#pragma unroll
            for (int i = 0; i < 4; ++i) {
                const float dt = us2f(bd[i]);
                const float xv = us2f(bx[i]);
                const float dtx = dt * xv;
                float w[8];
                pow_half8(__expf(dt * A0), (float)nh, w);
                float y = 0.0f;
#pragma unroll
                for (int k = 0; k < 8; ++k) {
                    h[k] = fmaf(w[k], h[k], dtx * Bsh[t0 + i][nb + k]);
                    y = fmaf(h[k], Csh[t0 + i][nb + k], y);
                }
                y += __shfl_xor(y, 1);   // combine the two n-halves
                const int tg = c * CHK + t0 + i;
                const int tm = rev ? (L_SEQ - 1 - tg) : tg;
                const float z = us2f(bz[i]);
                float yo = (y + Dd * xv) * silu_f(z);
                const size_t oi = (size_t)tm * D_INNER;
                if (acc) yo += us2f(y_base[oi]);
                if (g_base) yo *= silu_f(us2f(bg[i]));
                if (nh == 0) y_base[oi] = f2us(yo);
            }
            if (pf) {
#pragma unroll
                for (int i = 0; i < 4; ++i) { bd[i] = nd[i]; bx[i] = nx[i]; bz[i] = nz[i]; bg[i] = ng[i]; }
            }
        }
    } else {
        float Acoef[8];
#pragma unroll
        for (int k = 0; k < 8; ++k) Acoef[k] = -__expf(Alog[d * 16 + nb + k]);
        unsigned short vd = dtp[0], vx = xp[0];
        for (int t = 0; t < CHK; ++t) {
            unsigned short vd2 = 0, vx2 = 0;
            if (t + 1 < CHK) {
                vd2 = dtp[(size_t)(t + 1) * 1024];
                vx2 = xp[(size_t)(t + 1) * 1024];
            }
            const float dt = us2f(vd);
            const float xv = us2f(vx);
            const float dtx = dt * xv;
            float y = 0.0f;
#pragma unroll
            for (int k = 0; k < 8; ++k) {
                h[k] = fmaf(__expf(dt * Acoef[k]), h[k], dtx * Bsh[t][nb + k]);
                y = fmaf(h[k], Csh[t][nb + k], y);
            }
            y += __shfl_xor(y, 1);
            const int tg = c * CHK + t;
            const int tm = rev ? (L_SEQ - 1 - tg) : tg;
            const float z = us2f(z_base[(size_t)tm * 2048]);
            float yo = (y + Dd * xv) * silu_f(z);
            const size_t oi = (size_t)tm * D_INNER;
            if (acc) yo += us2f(y_base[oi]);
            if (g_base) yo *= silu_f(us2f(g_base[oi]));
            if (nh == 0) y_base[oi] = f2us(yo);
            vd = vd2; vx = vx2;
        }
    }
}

// ---------------------------------------------------------------------------
extern "C" void kernel_launch(void* const* d_in, const int* in_sizes, int n_in,
                              void* d_out, int out_size, void* d_ws, size_t ws_size,
                              hipStream_t stream)
{
    const float* hs    = (const float*)d_in[0];
    const float* ahs   = (const float*)d_in[1];
    const float* in_w  = (const float*)d_in[2];
    const float* in_gw = (const float*)d_in[3];
    const float* convw[3] = {(const float*)d_in[4], (const float*)d_in[6], (const float*)d_in[8]};
    const float* convb[3] = {(const float*)d_in[5], (const float*)d_in[7], (const float*)d_in[9]};
    const float* xproj[3] = {(const float*)d_in[10], (const float*)d_in[11], (const float*)d_in[12]};
    const float* dtw[3]   = {(const float*)d_in[13], (const float*)d_in[15], (const float*)d_in[17]};
    const float* dtbias[3]= {(const float*)d_in[14], (const float*)d_in[16], (const float*)d_in[18]};
    const float* Alog[3]  = {(const float*)d_in[19], (const float*)d_in[20], (const float*)d_in[21]};
    const float* Dp[3]    = {(const float*)d_in[22], (const float*)d_in[23], (const float*)d_in[24]};
    const float* out_w = (const float*)d_in[25];

    // Workspace (~228 MB, matches round-7 proven size):
    unsigned short* regA = (unsigned short*)d_ws;                    // M*2048 (axz then xz)
    float* dbl  = (float*)(regA + (size_t)M_ROWS * 2048);            // M*64 f32
    unsigned short* xb  = (unsigned short*)(dbl + (size_t)M_ROWS * 64); // M*1024
    unsigned short* dtv = xb  + (size_t)M_ROWS * 1024;               // M*1024
    unsigned short* yfr = dtv + (size_t)M_ROWS * 1024;               // M*1024 (first half = inb)
    unsigned short* yg  = yfr + (size_t)M_ROWS * 1024;               // M*1024
    float* hF   = (float*)(yg + (size_t)M_ROWS * 1024);              // B*NC*1024*16 f32
    float* Ssum = hF + (size_t)B_SZ * NC * 1024 * 16;                // B*NC*1024 f32
    unsigned short* dtin = (unsigned short*)(Ssum + (size_t)B_SZ * NC * 1024); // M*32
    unsigned short* wbig = dtin + (size_t)M_ROWS * 32;               // 2048*512
    unsigned short* wout = wbig + (size_t)2048 * 512;                // 512*1024
    unsigned short* wxpb = wout + (size_t)512 * 1024;                // 3 x 64*1024
    unsigned short* wdtb = wxpb + (size_t)3 * 64 * 1024;             // 3 x 1024*32
    unsigned short* inb  = yfr;   // 16 MB staging for bf16(ahs)/bf16(hs)

    const dim3 blk(256);

    // ---- cvt1: ahs + in_gw + out_w + xproj x3 + dtw x3 (one dispatch) ----
    {
        CvtArgs a;
        unsigned int acc = 0;
        const float* srcs[9] = {ahs, in_gw, out_w, xproj[0], xproj[1], xproj[2],
                                dtw[0], dtw[1], dtw[2]};
        unsigned short* dsts[9] = {inb, wbig, wout,
                                   wxpb, wxpb + 64 * 1024, wxpb + 2 * 64 * 1024,
                                   wdtb, wdtb + 1024 * 32, wdtb + 2 * 1024 * 32};
        const unsigned int sz[9] = {M_ROWS * 512u, 2048u * 512u, 512u * 1024u,
                                    64u * 1024u, 64u * 1024u, 64u * 1024u,
                                    1024u * 32u, 1024u * 32u, 1024u * 32u};
        for (int i = 0; i < 9; ++i) {
            a.src[i] = srcs[i]; a.dst[i] = dsts[i];
            acc += sz[i] / 4; a.vend[i] = acc;
        }
        a.nseg = 9;
        cvt_multi<<<dim3((acc + 255) / 256), blk, 0, stream>>>(a);
    }

    const int order[3] = {2, 0, 1};   // g, f, r

    // axz = bf16(ahs) @ in_proj_g^T -> regA   (SWZ=1: A re-read x16, L2 win)
    gemm_mfma<128,128,64,4,4,0,0,0,1><<<dim3(16, 128), blk, 0, stream>>>(
        inb, nullptr, wbig, nullptr, regA, nullptr, D_MODEL, D_MODEL, D_MODEL, 2048);

    for (int oi = 0; oi < 3; ++oi) {
        const int br = order[oi];
        const int rev  = (br == 1) ? 1 : 0;
        const int accf = (br == 1) ? 1 : 0;
        unsigned short* ybuf = (br == 2) ? yg : yfr;
        const unsigned short* gatep = (br == 1) ? yg : nullptr;

        if (br == 0) {
            // cvt2: hs + in_w into the (now free) inb/wbig buffers
            CvtArgs a;
            a.src[0] = hs;   a.dst[0] = inb;  a.vend[0] = M_ROWS * 512u / 4;
            a.src[1] = in_w; a.dst[1] = wbig; a.vend[1] = a.vend[0] + 2048u * 512u / 4;
            a.nseg = 2;
            cvt_multi<<<dim3((a.vend[1] + 255) / 256), blk, 0, stream>>>(a);
            gemm_mfma<128,128,64,4,4,0,0,0,1><<<dim3(16, 128), blk, 0, stream>>>(
                inb, nullptr, wbig, nullptr, regA, nullptr, D_MODEL, D_MODEL, D_MODEL, 2048);
        }

        conv_silu8<<<dim3(M_ROWS * 128 / 256), blk, 0, stream>>>(
            regA, convw[br], convb[br], xb, rev);

        // dbl = xb @ xproj^T (f32) + dual-write bf16 dtin (cols<32)  [SWZ=0]
        gemm_mfma<64,64,64,2,2,0,2,1,0><<<dim3(1, 256), blk, 0, stream>>>(
            xb, nullptr, wxpb + br * 64 * 1024, nullptr, dbl, dtin,
            D_INNER, D_INNER, D_INNER, 64);

        // dtv = softplus(dtin @ dtw^T + dtb), bf16 contiguous  [SWZ=0 --
        // round-5: blanket swizzle tripled this dispatch, 167.9us]
        gemm_mfma<128,128,32,4,4,0,1,0,0><<<dim3(8, 128), blk, 0, stream>>>(
            dtin, nullptr, wdtb + br * 1024 * 32, dtbias[br], dtv, nullptr,
            DT_RANK, DT_RANK, DT_RANK, D_INNER);

        scan_a<<<dim3(NC, 2, B_SZ), dim3(1024), 0, stream>>>(dtv, xb, dbl, Alog[br], hF, Ssum);
        scan_b<<<dim3((B_SZ * D_INNER * 16) / 256), blk, 0, stream>>>(hF, Ssum, Alog[br]);
        scan_c<<<dim3(NC, 2, B_SZ), dim3(1024), 0, stream>>>(
            dtv, xb, dbl, hF, Alog[br], Dp[br], regA, ybuf, gatep, rev, accf);
    }

    // out = ygated @ out_proj^T (plain DMA-staged GEMM; gate fused into
    // branch-r scan_c)  [SWZ=0]
    gemm_mfma<128,128,64,4,4,0,0,1,0><<<dim3(4, 128), blk, 0, stream>>>(
        yfr, nullptr, wout, nullptr, d_out, nullptr, D_INNER, D_INNER, D_INNER, D_MODEL);
}

// Round 17
// 957.273 us; speedup vs baseline: 1.2806x; 1.2806x over previous
//
#include <hip/hip_runtime.h>
#include <hip/hip_bf16.h>
#include <math.h>

#define L_SEQ 4096
#define B_SZ 4
#define D_MODEL 512
#define D_INNER 1024
#define DT_RANK 32
#define D_STATE 16
#define M_ROWS (B_SZ * L_SEQ)   // 16384
#define NC 64                    // chunks per sequence
#define CHK (L_SEQ / NC)         // 64 steps per chunk

typedef __hip_bfloat16 bf16;
typedef __bf16 bf16x8 __attribute__((ext_vector_type(8)));
typedef float f32x4 __attribute__((ext_vector_type(4)));
struct us8 { ushort4 a, b; };    // 16-byte chunk of 8 bf16 bit patterns

// ---- bf16 bit conversions -------------------------------------------------
__device__ __forceinline__ unsigned short f2us(float f) {
    union { bf16 h; unsigned short u; } t;
    t.h = __float2bfloat16(f);
    return t.u;
}
__device__ __forceinline__ float us2f(unsigned short u) {
    union { bf16 h; unsigned short u; } t;
    t.u = u;
    return __bfloat162float(t.h);
}

// ---- hardened transcendentals ---------------------------------------------
__device__ __forceinline__ float silu_f(float x) {
    const float xc = fminf(fmaxf(x, -60.0f), 60.0f);
    return x / (1.0f + __expf(-xc));
}
__device__ __forceinline__ float softplus_f(float x) {
    if (x > 20.0f) return x;
    if (x < -20.0f) return __expf(x);
    return log1pf(__expf(x));
}

// ---------------------------------------------------------------------------
// Fused multi-segment f32 -> bf16 conversion (one dispatch for many tensors).
// ---------------------------------------------------------------------------
struct CvtArgs {
    const float* src[9];
    unsigned short* dst[9];
    unsigned int vend[9];   // cumulative vec4 counts
    int nseg;
};
__global__ __launch_bounds__(256)
void cvt_multi(CvtArgs a)
{
    const unsigned int v = blockIdx.x * 256 + threadIdx.x;
    if (v >= a.vend[a.nseg - 1]) return;
    int s = 0;
    unsigned int vstart = 0;
    while (v >= a.vend[s]) { vstart = a.vend[s]; ++s; }
    const size_t lv = (size_t)(v - vstart) * 4;
    const float4 f = *(const float4*)(a.src[s] + lv);
    ushort4 o;
    o.x = f2us(f.x); o.y = f2us(f.y); o.z = f2us(f.z); o.w = f2us(f.w);
    *(ushort4*)(a.dst[s] + lv) = o;
}

// ---------------------------------------------------------------------------
// MFMA bf16 "NT" GEMM v2: C[m,n] = sum_k A[m,k]*W[n,k], f32 accumulate.
// Staging via global_load_lds (16B DMA) into XOR-swizzled LDS.
// SWZ=1: XCD-chunked bijective blockIdx remap -- ONLY for the big in-proj
// GEMMs (A re-read x16 across col-blocks; per-XCD working set -> L2-sized).
// Round-5 lesson: blanket swizzle tripled the dtv GEMM (167.9 vs <=71 us),
// so it is opt-in per instantiation.
// GATED==1: A element = A*silu(A2), staged by VALU (same swizzle).
// EPI: 0 none; 1 softplus(acc+bias[n]); 2 dual write f32 C + bf16 C2 (n<32).
// CT : 0 C bf16, 1 C f32. Block 256 = 4 waves, wave tile (WY*16)x(WX*16).
// ---------------------------------------------------------------------------
template<int BM, int BN, int BK, int WY, int WX, int GATED, int EPI, int CT, int SWZ>
__global__ __launch_bounds__(256)
void gemm_mfma(const unsigned short* __restrict__ A,
               const unsigned short* __restrict__ A2,
               const unsigned short* __restrict__ W,
               const float* __restrict__ bias,
               void* __restrict__ Cp, unsigned short* __restrict__ C2p,
               int K, int lda, int ldb, int ldc)
{
    constexpr int CPR = BK / 8;        // 16B chunks per LDS row
    constexpr int SWM = CPR - 1;
    constexpr int RPW = 64 / CPR;      // rows per wave per DMA pass
    constexpr int NPA = BM / (4 * RPW);
    constexpr int NPB = BN / (4 * RPW);
    constexpr int WGX = BN / (WX * 16);
    static_assert(WGX * (BM / (WY * 16)) == 4, "4 waves");
    __shared__ unsigned short As[BM * BK];
    __shared__ unsigned short Bs[BN * BK];

    const int tid  = threadIdx.x;
    const int lane = tid & 63;
    const int wave = tid >> 6;
    const int wx = wave % WGX, wy = wave / WGX;
    const int l15 = lane & 15, quad = lane >> 4;

    int bid = blockIdx.y * gridDim.x + blockIdx.x;
    if (SWZ) {
        const int nwg = gridDim.x * gridDim.y;
        if ((nwg & 7) == 0) {
            const int cpx = nwg >> 3;
            bid = (bid & 7) * cpx + (bid >> 3);
        }
    }
    const int bxi = bid % gridDim.x;
    const int byi = bid / gridDim.x;
    const long row0 = (long)byi * BM;
    const long col0 = (long)bxi * BN;

    // DMA lane mapping: lane -> (row-in-pass, swizzled source chunk)
    const int rin = lane / CPR;
    const int gc  = (lane % CPR) ^ (rin & SWM);

    f32x4 acc[WY][WX];
#pragma unroll
    for (int i = 0; i < WY; ++i)
#pragma unroll
        for (int j = 0; j < WX; ++j) acc[i][j] = (f32x4){0.f, 0.f, 0.f, 0.f};

    for (int k0 = 0; k0 < K; k0 += BK) {
        if (GATED == 0) {
#pragma unroll
            for (int p = 0; p < NPA; ++p) {
                const int rb = (p * 4 + wave) * RPW;
                const unsigned short* gp = A + (row0 + rb + rin) * (long)lda + k0 + gc * 8;
                const int lb = __builtin_amdgcn_readfirstlane(rb * BK);
                __builtin_amdgcn_global_load_lds(
                    (const __attribute__((address_space(1))) void*)gp,
                    (__attribute__((address_space(3))) void*)(As + lb), 16, 0, 0);
            }
        } else {
#pragma unroll
            for (int v = 0; v < BM * BK / 2048; ++v) {
                const int e = (v * 256 + tid) * 8;
                const int r = e / BK, c = (e % BK) / 8;
                const long off = (row0 + r) * (long)lda + k0 + c * 8;
                const us8 ta = *(const us8*)(A + off);
                const us8 tg = *(const us8*)(A2 + off);
                us8 t;
                t.a.x = f2us(us2f(ta.a.x) * silu_f(us2f(tg.a.x)));
                t.a.y = f2us(us2f(ta.a.y) * silu_f(us2f(tg.a.y)));
                t.a.z = f2us(us2f(ta.a.z) * silu_f(us2f(tg.a.z)));
                t.a.w = f2us(us2f(ta.a.w) * silu_f(us2f(tg.a.w)));
                t.b.x = f2us(us2f(ta.b.x) * silu_f(us2f(tg.b.x)));
                t.b.y = f2us(us2f(ta.b.y) * silu_f(us2f(tg.b.y)));
                t.b.z = f2us(us2f(ta.b.z) * silu_f(us2f(tg.b.z)));
                t.b.w = f2us(us2f(ta.b.w) * silu_f(us2f(tg.b.w)));
                *(us8*)&As[r * BK + ((c ^ (r & SWM)) * 8)] = t;
            }
        }
#pragma unroll
        for (int p = 0; p < NPB; ++p) {
            const int rb = (p * 4 + wave) * RPW;
            const unsigned short* gp = W + (col0 + rb + rin) * (long)ldb + k0 + gc * 8;
            const int lb = __builtin_amdgcn_readfirstlane(rb * BK);
            __builtin_amdgcn_global_load_lds(
                (const __attribute__((address_space(1))) void*)gp,
                (__attribute__((address_space(3))) void*)(Bs + lb), 16, 0, 0);
        }
        __syncthreads();   // drains vmcnt (DMA) + lgkmcnt before LDS reads

#pragma unroll
        for (int kk = 0; kk < BK / 32; ++kk) {
            bf16x8 aF[WY], bF[WX];
#pragma unroll
            for (int i = 0; i < WY; ++i) {
                const int r  = wy * WY * 16 + i * 16 + l15;
                const int kc = (kk * 4 + quad) ^ (r & SWM);
                aF[i] = *(const bf16x8*)&As[r * BK + kc * 8];
            }
#pragma unroll
            for (int j = 0; j < WX; ++j) {
                const int r  = wx * WX * 16 + j * 16 + l15;
                const int kc = (kk * 4 + quad) ^ (r & SWM);
                bF[j] = *(const bf16x8*)&Bs[r * BK + kc * 8];
            }
#pragma unroll
            for (int i = 0; i < WY; ++i)
#pragma unroll
                for (int j = 0; j < WX; ++j)
                    acc[i][j] = __builtin_amdgcn_mfma_f32_16x16x32_bf16(
                        aF[i], bF[j], acc[i][j], 0, 0, 0);
        }
        __syncthreads();
    }

    // ---- epilogue: lane holds rows quad*4+r, col l15 of each 16x16 tile ----
#pragma unroll
    for (int i = 0; i < WY; ++i)
#pragma unroll
        for (int j = 0; j < WX; ++j) {
            const long mb = row0 + wy * WY * 16 + i * 16 + quad * 4;
            const long n  = col0 + wx * WX * 16 + j * 16 + l15;
            const float bv = (EPI == 1) ? bias[n] : 0.0f;
#pragma unroll
            for (int r = 0; r < 4; ++r) {
                float val = acc[i][j][r];
                if (EPI == 1) val = softplus_f(val + bv);
                const long off = (mb + r) * (long)ldc + n;
                if (CT == 0) ((unsigned short*)Cp)[off] = f2us(val);
                else         ((float*)Cp)[off] = val;
                if (EPI == 2 && n < DT_RANK) C2p[(mb + r) * DT_RANK + n] = f2us(val);
            }
        }
}

// ---------------------------------------------------------------------------
// Depthwise causal conv1d (k=4) + bias + SiLU, 8 d-elements per thread.
// ---------------------------------------------------------------------------
__global__ __launch_bounds__(256)
void conv_silu8(const unsigned short* __restrict__ xz, const float* __restrict__ w,
                const float* __restrict__ bias, unsigned short* __restrict__ xb, int rev)
{
    const int idx = blockIdx.x * 256 + threadIdx.x;   // over M_ROWS * 128
    const int g = idx & 127;
    const int m = idx >> 7;
    const int b = m >> 12;
    const int t = m & (L_SEQ - 1);
    const int d = g * 8;

    float s[8];
    {
        const float4 b0 = *(const float4*)(bias + d);
        const float4 b1 = *(const float4*)(bias + d + 4);
        s[0] = b0.x; s[1] = b0.y; s[2] = b0.z; s[3] = b0.w;
        s[4] = b1.x; s[5] = b1.y; s[6] = b1.z; s[7] = b1.w;
    }
    float4 wv[8];
#pragma unroll
    for (int j = 0; j < 8; ++j) wv[j] = *(const float4*)(w + (d + j) * 4);

    const unsigned short* xbase = xz + (size_t)b * L_SEQ * 2048 + d;
#pragma unroll
    for (int k = 0; k < 4; ++k) {
        const int src = t - 3 + k;
        if (src >= 0) {
            const int sm = rev ? (L_SEQ - 1 - src) : src;
            const us8 xv = *(const us8*)(xbase + (size_t)sm * 2048);
            const float tap[8] = {us2f(xv.a.x), us2f(xv.a.y), us2f(xv.a.z), us2f(xv.a.w),
                                  us2f(xv.b.x), us2f(xv.b.y), us2f(xv.b.z), us2f(xv.b.w)};
#pragma unroll
            for (int j = 0; j < 8; ++j) {
                const float wk = (k == 0) ? wv[j].x : (k == 1) ? wv[j].y
                               : (k == 2) ? wv[j].z : wv[j].w;
                s[j] = fmaf(wk, tap[j], s[j]);
            }
        }
    }
    us8 o;
    o.a.x = f2us(silu_f(s[0])); o.a.y = f2us(silu_f(s[1]));
    o.a.z = f2us(silu_f(s[2])); o.a.w = f2us(silu_f(s[3]));
    o.b.x = f2us(silu_f(s[4])); o.b.y = f2us(silu_f(s[5]));
    o.b.z = f2us(silu_f(s[6])); o.b.w = f2us(silu_f(s[7]));
    *(us8*)(xb + (size_t)m * 1024 + d) = o;
}

// ---------------------------------------------------------------------------
// A-structure probe + power tree (verified rounds 2/6: absmax 7.6e-06).
// ---------------------------------------------------------------------------
__device__ __forceinline__ bool a_struct_fast(const float* __restrict__ Alog,
                                              int d, float& A0)
{
    A0 = -__expf(Alog[d * 16]);
    bool fast = true;
#pragma unroll
    for (int n = 1; n < 16; ++n) {
        const float an = -__expf(Alog[d * 16 + n]);
        const float tg = (float)(n + 1) * A0;
        fast = fast && (fabsf(an - tg) <= 1e-5f * fabsf(tg));
    }
    return fast;
}
__device__ __forceinline__ void pow_tree16(float e1, float w[16])
{
    w[0] = e1;
    w[1] = w[0] * w[0];  w[2] = w[1] * w[0];  w[3] = w[1] * w[1];
    w[4] = w[3] * w[0];  w[5] = w[3] * w[1];  w[6] = w[3] * w[2];  w[7] = w[3] * w[3];
#pragma unroll
    for (int n = 8; n < 16; ++n) w[n] = w[7] * w[n - 8];
}

// ---------------------------------------------------------------------------
// Chunked selective scan, phase A. ROUND-6 STRUCTURE (1024 thr, grid (NC,B)):
// round-11/14 lessons: (a) block-split is an occupancy no-op (total threads
// cap), (b) lane-pair n-split raised occupancy 32->83% but quadrupled HBM
// traffic (half-wave 2B stores + pair-duplicated loads) -> 2.4x slower.
// This round: scan is LDS-ISSUE bound (32 scalar ds_read_b32/step ~= the
// measured 76us) -> force float4 LDS reads (4x fewer LDS instructions).
// ---------------------------------------------------------------------------
__global__ __launch_bounds__(1024)
void scan_a(const unsigned short* __restrict__ dtq, const unsigned short* __restrict__ xq,
            const float* __restrict__ dbl, const float* __restrict__ Alog,
            float* __restrict__ hF, float* __restrict__ Ssum)
{
    const int d = threadIdx.x;
    const int c = blockIdx.x;
    const int b = blockIdx.y;

    __shared__ float Bsh[CHK][16];
    {
        const int tl = d >> 4, nl = d & 15;
        Bsh[tl][nl] = dbl[((size_t)b * L_SEQ + c * CHK + tl) * 64 + DT_RANK + nl];
    }
    __syncthreads();

    float A0;
    const bool fast = a_struct_fast(Alog, d, A0);

    float h[16];
#pragma unroll
    for (int n = 0; n < 16; ++n) h[n] = 0.0f;
    float S = 0.0f;

    const size_t base = ((size_t)b * L_SEQ + c * CHK) * 1024 + d;
    const unsigned short* dtp = dtq + base;
    const unsigned short* xp  = xq + base;

    if (fast) {
        unsigned short bd[4], bx[4];
#pragma unroll
        for (int i = 0; i < 4; ++i) {
            bd[i] = dtp[(size_t)i * 1024];
            bx[i] = xp[(size_t)i * 1024];
        }
        for (int t0 = 0; t0 < CHK; t0 += 4) {
            unsigned short nd[4], nx[4];
            const bool pf = (t0 + 4 < CHK);
            if (pf) {
#pragma unroll
                for (int i = 0; i < 4; ++i) {
                    nd[i] = dtp[(size_t)(t0 + 4 + i) * 1024];
                    nx[i] = xp[(size_t)(t0 + 4 + i) * 1024];
                }
            }
#pragma unroll
            for (int i = 0; i < 4; ++i) {
                const float dt = us2f(bd[i]);
                const float xv = us2f(bx[i]);
                S += dt;
                const float dtx = dt * xv;
                float w[16];
                pow_tree16(__expf(dt * A0), w);
                // float4 LDS reads: 4x ds_read_b128 instead of 16x b32
                float bv[16];
                *(float4*)&bv[0]  = *(const float4*)&Bsh[t0 + i][0];
                *(float4*)&bv[4]  = *(const float4*)&Bsh[t0 + i][4];
                *(float4*)&bv[8]  = *(const float4*)&Bsh[t0 + i][8];
                *(float4*)&bv[12] = *(const float4*)&Bsh[t0 + i][12];
#pragma unroll
                for (int n = 0; n < 16; ++n)
                    h[n] = fmaf(w[n], h[n], dtx * bv[n]);
            }
            if (pf) {
#pragma unroll
                for (int i = 0; i < 4; ++i) { bd[i] = nd[i]; bx[i] = nx[i]; }
            }
        }
    } else {
        float Acoef[16];
#pragma unroll
        for (int n = 0; n < 16; ++n) Acoef[n] = -__expf(Alog[d * 16 + n]);
        unsigned short vd = dtp[0], vx = xp[0];
        for (int t = 0; t < CHK; ++t) {
            unsigned short vd2 = 0, vx2 = 0;
            if (t + 1 < CHK) {
                vd2 = dtp[(size_t)(t + 1) * 1024];
                vx2 = xp[(size_t)(t + 1) * 1024];
            }
            const float dt = us2f(vd);
            const float xv = us2f(vx);
            S += dt;
            const float dtx = dt * xv;
#pragma unroll
            for (int n = 0; n < 16; ++n)
                h[n] = fmaf(__expf(dt * Acoef[n]), h[n], dtx * Bsh[t][n]);
            vd = vd2; vx = vx2;
        }
    }

    float* hp = hF + (((size_t)(b * NC + c) * 1024 + d) << 4);
#pragma unroll
    for (int n = 0; n < 16; ++n) hp[n] = h[n];
    Ssum[(size_t)(b * NC + c) * 1024 + d] = S;
}

// ---------------------------------------------------------------------------
// Phase B: sequential combine over chunks.
// ---------------------------------------------------------------------------
__global__ __launch_bounds__(256)
void scan_b(float* __restrict__ hF, const float* __restrict__ Ssum,
            const float* __restrict__ Alog)
{
    const int idx = blockIdx.x * 256 + threadIdx.x;   // B*D*16
    const int n  = idx & 15;
    const int dn = idx >> 4;
    const int d  = dn & (D_INNER - 1);
    const int b  = dn >> 10;

    const float Acoef = -__expf(Alog[d * 16 + n]);
    float H = 0.0f;
    for (int c = 0; c < NC; ++c) {
        const size_t base = (size_t)(b * NC + c) * 1024 + d;
        const float S = Ssum[base];
        float* hp = hF + (base << 4) + n;
        const float hOld = *hp;
        *hp = H;
        H = fmaf(__expf(Acoef * S), H, hOld);
    }
}

// ---------------------------------------------------------------------------
// Phase C: re-run chunk from true h_init; fused D*x + silu(z) gate; rev maps
// back to original time order; acc=1 accumulates (branch r into yfr).
// gate!=nullptr (branch r): final output = (yfr_old + y_r) * silu(gate[oi]).
// ROUND-6 STRUCTURE + float4 LDS reads (see scan_a note).
// ---------------------------------------------------------------------------
__global__ __launch_bounds__(1024)
void scan_c(const unsigned short* __restrict__ dtq, const unsigned short* __restrict__ xq,
            const float* __restrict__ dbl, const float* __restrict__ hF,
            const float* __restrict__ Alog, const float* __restrict__ Dp,
            const unsigned short* __restrict__ xz, unsigned short* __restrict__ yout,
            const unsigned short* __restrict__ gate, int rev, int acc)
{
    const int d = threadIdx.x;
    const int c = blockIdx.x;
    const int b = blockIdx.y;

    __shared__ float Bsh[CHK][16];
    __shared__ float Csh[CHK][16];
    {
        const int tl = d >> 4, nl = d & 15;
        const size_t rb = ((size_t)b * L_SEQ + c * CHK + tl) * 64;
        Bsh[tl][nl] = dbl[rb + DT_RANK + nl];
        Csh[tl][nl] = dbl[rb + DT_RANK + D_STATE + nl];
    }
    __syncthreads();

    float A0;
    const bool fast = a_struct_fast(Alog, d, A0);
    const float Dd = Dp[d];

    float h[16];
    {
        const float* hp = hF + (((size_t)(b * NC + c) * 1024 + d) << 4);
#pragma unroll
        for (int n = 0; n < 16; ++n) h[n] = hp[n];
    }

    const size_t base = ((size_t)b * L_SEQ + c * CHK) * 1024 + d;
    const unsigned short* dtp = dtq + base;
    const unsigned short* xp  = xq + base;
    const unsigned short* z_base = xz + (size_t)b * L_SEQ * 2048 + D_INNER + d;
    const unsigned short* g_base = gate ? gate + (size_t)b * L_SEQ * D_INNER + d : nullptr;
    unsigned short* y_base = yout + (size_t)b * L_SEQ * D_INNER + d;

    if (fast) {
        unsigned short bd[4], bx[4], bz[4], bg[4];
#pragma unroll
        for (int i = 0; i < 4; ++i) {
            bd[i] = dtp[(size_t)i * 1024];
            bx[i] = xp[(size_t)i * 1024];
            const int tg = c * CHK + i;
            const int tm = rev ? (L_SEQ - 1 - tg) : tg;
            bz[i] = z_base[(size_t)tm * 2048];
            bg[i] = g_base ? g_base[(size_t)tm * D_INNER] : (unsigned short)0;
        }
        for (int t0 = 0; t0 < CHK; t0 += 4) {
            unsigned short nd[4], nx[4], nz[4], ng[4];
            const bool pf = (t0 + 4 < CHK);
            if (pf) {
#pragma unroll
                for (int i = 0; i < 4; ++i) {
                    nd[i] = dtp[(size_t)(t0 + 4 + i) * 1024];
                    nx[i] = xp[(size_t)(t0 + 4 + i) * 1024];
                    const int tg = c * CHK + t0 + 4 + i;
                    const int tm = rev ? (L_SEQ - 1 - tg) : tg;
                    nz[i] = z_base[(size_t)tm * 2048];
                    ng[i] = g_base ? g_base[(size_t)tm * D_INNER] : (unsigned short)0;
                }
            }
#pragma unroll
            for (int i = 0; i < 4; ++i) {
                const float dt = us2f(bd[i]);
                const float xv = us2f(bx[i]);
                const float dtx = dt * xv;
                float w[16];
                pow_tree16(__expf(dt * A0), w);
                // float4 LDS reads: 8x ds_read_b128 instead of 32x b32
                float bv[16], cv[16];
                *(float4*)&bv[0]  = *(const float4*)&Bsh[t0 + i][0];
                *(float4*)&bv[4]  = *(const float4*)&Bsh[t0 + i][4];
                *(float4*)&bv[8]  = *(const float4*)&Bsh[t0 + i][8];
                *(float4*)&bv[12] = *(const float4*)&Bsh[t0 + i][12];
                *(float4*)&cv[0]  = *(const float4*)&Csh[t0 + i][0];
                *(float4*)&cv[4]  = *(const float4*)&Csh[t0 + i][4];
                *(float4*)&cv[8]  = *(const float4*)&Csh[t0 + i][8];
                *(float4*)&cv[12] = *(const float4*)&Csh[t0 + i][12];
                float y = 0.0f;
#pragma unroll
                for (int n = 0; n < 16; ++n) {
                    h[n] = fmaf(w[n], h[n], dtx * bv[n]);
                    y = fmaf(h[n], cv[n], y);
                }
                const int tg = c * CHK + t0 + i;
                const int tm = rev ? (L_SEQ - 1 - tg) : tg;
                const float z = us2f(bz[i]);
                float yo = (y + Dd * xv) * silu_f(z);
                const size_t oi = (size_t)tm * D_INNER;
                if (acc) yo += us2f(y_base[oi]);
                if (g_base) yo *= silu_f(us2f(bg[i]));
                y_base[oi] = f2us(yo);
            }
            if (pf) {
#pragma unroll
                for (int i = 0; i < 4; ++i) { bd[i] = nd[i]; bx[i] = nx[i]; bz[i] = nz[i]; bg[i] = ng[i]; }
            }
        }
    } else {
        float Acoef[16];
#pragma unroll
        for (int n = 0; n < 16; ++n) Acoef[n] = -__expf(Alog[d * 16 + n]);
        unsigned short vd = dtp[0], vx = xp[0];
        for (int t = 0; t < CHK; ++t) {
            unsigned short vd2 = 0, vx2 = 0;
            if (t + 1 < CHK) {
                vd2 = dtp[(size_t)(t + 1) * 1024];
                vx2 = xp[(size_t)(t + 1) * 1024];
            }
            const float dt = us2f(vd);
            const float xv = us2f(vx);
            const float dtx = dt * xv;
            float y = 0.0f;
#pragma unroll
            for (int n = 0; n < 16; ++n) {
                h[n] = fmaf(__expf(dt * Acoef[n]), h[n], dtx * Bsh[t][n]);
                y = fmaf(h[n], Csh[t][n], y);
            }
            const int tg = c * CHK + t;
            const int tm = rev ? (L_SEQ - 1 - tg) : tg;
            const float z = us2f(z_base[(size_t)tm * 2048]);
            float yo = (y + Dd * xv) * silu_f(z);
            const size_t oi = (size_t)tm * D_INNER;
            if (acc) yo += us2f(y_base[oi]);
            if (g_base) yo *= silu_f(us2f(g_base[oi]));
            y_base[oi] = f2us(yo);
            vd = vd2; vx = vx2;
        }
    }
}

// ---------------------------------------------------------------------------
extern "C" void kernel_launch(void* const* d_in, const int* in_sizes, int n_in,
                              void* d_out, int out_size, void* d_ws, size_t ws_size,
                              hipStream_t stream)
{
    const float* hs    = (const float*)d_in[0];
    const float* ahs   = (const float*)d_in[1];
    const float* in_w  = (const float*)d_in[2];
    const float* in_gw = (const float*)d_in[3];
    const float* convw[3] = {(const float*)d_in[4], (const float*)d_in[6], (const float*)d_in[8]};
    const float* convb[3] = {(const float*)d_in[5], (const float*)d_in[7], (const float*)d_in[9]};
    const float* xproj[3] = {(const float*)d_in[10], (const float*)d_in[11], (const float*)d_in[12]};
    const float* dtw[3]   = {(const float*)d_in[13], (const float*)d_in[15], (const float*)d_in[17]};
    const float* dtbias[3]= {(const float*)d_in[14], (const float*)d_in[16], (const float*)d_in[18]};
    const float* Alog[3]  = {(const float*)d_in[19], (const float*)d_in[20], (const float*)d_in[21]};
    const float* Dp[3]    = {(const float*)d_in[22], (const float*)d_in[23], (const float*)d_in[24]};
    const float* out_w = (const float*)d_in[25];

    // Workspace (~228 MB, matches round-7 proven size):
    unsigned short* regA = (unsigned short*)d_ws;                    // M*2048 (axz then xz)
    float* dbl  = (float*)(regA + (size_t)M_ROWS * 2048);            // M*64 f32
    unsigned short* xb  = (unsigned short*)(dbl + (size_t)M_ROWS * 64); // M*1024
    unsigned short* dtv = xb  + (size_t)M_ROWS * 1024;               // M*1024
    unsigned short* yfr = dtv + (size_t)M_ROWS * 1024;               // M*1024 (first half = inb)
    unsigned short* yg  = yfr + (size_t)M_ROWS * 1024;               // M*1024
    float* hF   = (float*)(yg + (size_t)M_ROWS * 1024);              // B*NC*1024*16 f32
    float* Ssum = hF + (size_t)B_SZ * NC * 1024 * 16;                // B*NC*1024 f32
    unsigned short* dtin = (unsigned short*)(Ssum + (size_t)B_SZ * NC * 1024); // M*32
    unsigned short* wbig = dtin + (size_t)M_ROWS * 32;               // 2048*512
    unsigned short* wout = wbig + (size_t)2048 * 512;                // 512*1024
    unsigned short* wxpb = wout + (size_t)512 * 1024;                // 3 x 64*1024
    unsigned short* wdtb = wxpb + (size_t)3 * 64 * 1024;             // 3 x 1024*32
    unsigned short* inb  = yfr;   // 16 MB staging for bf16(ahs)/bf16(hs)

    const dim3 blk(256);

    // ---- cvt1: ahs + in_gw + out_w + xproj x3 + dtw x3 (one dispatch) ----
    {
        CvtArgs a;
        unsigned int acc = 0;
        const float* srcs[9] = {ahs, in_gw, out_w, xproj[0], xproj[1], xproj[2],
                                dtw[0], dtw[1], dtw[2]};
        unsigned short* dsts[9] = {inb, wbig, wout,
                                   wxpb, wxpb + 64 * 1024, wxpb + 2 * 64 * 1024,
                                   wdtb, wdtb + 1024 * 32, wdtb + 2 * 1024 * 32};
        const unsigned int sz[9] = {M_ROWS * 512u, 2048u * 512u, 512u * 1024u,
                                    64u * 1024u, 64u * 1024u, 64u * 1024u,
                                    1024u * 32u, 1024u * 32u, 1024u * 32u};
        for (int i = 0; i < 9; ++i) {
            a.src[i] = srcs[i]; a.dst[i] = dsts[i];
            acc += sz[i] / 4; a.vend[i] = acc;
        }
        a.nseg = 9;
        cvt_multi<<<dim3((acc + 255) / 256), blk, 0, stream>>>(a);
    }

    const int order[3] = {2, 0, 1};   // g, f, r

    // axz = bf16(ahs) @ in_proj_g^T -> regA   (SWZ=1: A re-read x16, L2 win)
    gemm_mfma<128,128,64,4,4,0,0,0,1><<<dim3(16, 128), blk, 0, stream>>>(
        inb, nullptr, wbig, nullptr, regA, nullptr, D_MODEL, D_MODEL, D_MODEL, 2048);

    for (int oi = 0; oi < 3; ++oi) {
        const int br = order[oi];
        const int rev  = (br == 1) ? 1 : 0;
        const int accf = (br == 1) ? 1 : 0;
        unsigned short* ybuf = (br == 2) ? yg : yfr;
        const unsigned short* gatep = (br == 1) ? yg : nullptr;

        if (br == 0) {
            // cvt2: hs + in_w into the (now free) inb/wbig buffers
            CvtArgs a;
            a.src[0] = hs;   a.dst[0] = inb;  a.vend[0] = M_ROWS * 512u / 4;
            a.src[1] = in_w; a.dst[1] = wbig; a.vend[1] = a.vend[0] + 2048u * 512u / 4;
            a.nseg = 2;
            cvt_multi<<<dim3((a.vend[1] + 255) / 256), blk, 0, stream>>>(a);
            gemm_mfma<128,128,64,4,4,0,0,0,1><<<dim3(16, 128), blk, 0, stream>>>(
                inb, nullptr, wbig, nullptr, regA, nullptr, D_MODEL, D_MODEL, D_MODEL, 2048);
        }

        conv_silu8<<<dim3(M_ROWS * 128 / 256), blk, 0, stream>>>(
            regA, convw[br], convb[br], xb, rev);

        // dbl = xb @ xproj^T (f32) + dual-write bf16 dtin (cols<32)  [SWZ=0]
        gemm_mfma<64,64,64,2,2,0,2,1,0><<<dim3(1, 256), blk, 0, stream>>>(
            xb, nullptr, wxpb + br * 64 * 1024, nullptr, dbl, dtin,
            D_INNER, D_INNER, D_INNER, 64);

        // dtv = softplus(dtin @ dtw^T + dtb), bf16 contiguous  [SWZ=0 --
        // round-5: blanket swizzle tripled this dispatch, 167.9us]
        gemm_mfma<128,128,32,4,4,0,1,0,0><<<dim3(8, 128), blk, 0, stream>>>(
            dtin, nullptr, wdtb + br * 1024 * 32, dtbias[br], dtv, nullptr,
            DT_RANK, DT_RANK, DT_RANK, D_INNER);

        scan_a<<<dim3(NC, B_SZ), dim3(1024), 0, stream>>>(dtv, xb, dbl, Alog[br], hF, Ssum);
        scan_b<<<dim3((B_SZ * D_INNER * 16) / 256), blk, 0, stream>>>(hF, Ssum, Alog[br]);
        scan_c<<<dim3(NC, B_SZ), dim3(1024), 0, stream>>>(
            dtv, xb, dbl, hF, Alog[br], Dp[br], regA, ybuf, gatep, rev, accf);
    }

    // out = ygated @ out_proj^T (plain DMA-staged GEMM; gate fused into
    // branch-r scan_c)  [SWZ=0]
    gemm_mfma<128,128,64,4,4,0,0,1,0><<<dim3(4, 128), blk, 0, stream>>>(
        yfr, nullptr, wout, nullptr, d_out, nullptr, D_INNER, D_INNER, D_INNER, D_MODEL);
}

// Round 18
// 955.522 us; speedup vs baseline: 1.2829x; 1.0018x over previous
//
#include <hip/hip_runtime.h>
#include <hip/hip_bf16.h>
#include <math.h>

#define L_SEQ 4096
#define B_SZ 4
#define D_MODEL 512
#define D_INNER 1024
#define DT_RANK 32
#define D_STATE 16
#define M_ROWS (B_SZ * L_SEQ)   // 16384
#define NC 64                    // chunks per sequence
#define CHK (L_SEQ / NC)         // 64 steps per chunk

typedef __hip_bfloat16 bf16;
typedef __bf16 bf16x8 __attribute__((ext_vector_type(8)));
typedef float f32x4 __attribute__((ext_vector_type(4)));
typedef float f32x2 __attribute__((ext_vector_type(2)));
struct us8 { ushort4 a, b; };    // 16-byte chunk of 8 bf16 bit patterns

// ---- bf16 bit conversions -------------------------------------------------
__device__ __forceinline__ unsigned short f2us(float f) {
    union { bf16 h; unsigned short u; } t;
    t.h = __float2bfloat16(f);
    return t.u;
}
__device__ __forceinline__ float us2f(unsigned short u) {
    union { bf16 h; unsigned short u; } t;
    t.u = u;
    return __bfloat162float(t.h);
}

// ---- hardened transcendentals ---------------------------------------------
__device__ __forceinline__ float silu_f(float x) {
    const float xc = fminf(fmaxf(x, -60.0f), 60.0f);
    return x / (1.0f + __expf(-xc));
}
__device__ __forceinline__ float softplus_f(float x) {
    if (x > 20.0f) return x;
    if (x < -20.0f) return __expf(x);
    return log1pf(__expf(x));
}

// ---------------------------------------------------------------------------
// Fused multi-segment f32 -> bf16 conversion (one dispatch for many tensors).
// ---------------------------------------------------------------------------
struct CvtArgs {
    const float* src[9];
    unsigned short* dst[9];
    unsigned int vend[9];   // cumulative vec4 counts
    int nseg;
};
__global__ __launch_bounds__(256)
void cvt_multi(CvtArgs a)
{
    const unsigned int v = blockIdx.x * 256 + threadIdx.x;
    if (v >= a.vend[a.nseg - 1]) return;
    int s = 0;
    unsigned int vstart = 0;
    while (v >= a.vend[s]) { vstart = a.vend[s]; ++s; }
    const size_t lv = (size_t)(v - vstart) * 4;
    const float4 f = *(const float4*)(a.src[s] + lv);
    ushort4 o;
    o.x = f2us(f.x); o.y = f2us(f.y); o.z = f2us(f.z); o.w = f2us(f.w);
    *(ushort4*)(a.dst[s] + lv) = o;
}

// ---------------------------------------------------------------------------
// MFMA bf16 "NT" GEMM v2: C[m,n] = sum_k A[m,k]*W[n,k], f32 accumulate.
// Staging via global_load_lds (16B DMA) into XOR-swizzled LDS.
// SWZ=1: XCD-chunked bijective blockIdx remap -- ONLY for the big in-proj
// GEMMs (A re-read x16 across col-blocks; per-XCD working set -> L2-sized).
// Round-5 lesson: blanket swizzle tripled the dtv GEMM (167.9 vs <=71 us),
// so it is opt-in per instantiation.
// GATED==1: A element = A*silu(A2), staged by VALU (same swizzle).
// EPI: 0 none; 1 softplus(acc+bias[n]); 2 dual write f32 C + bf16 C2 (n<32).
// CT : 0 C bf16, 1 C f32. Block 256 = 4 waves, wave tile (WY*16)x(WX*16).
// ---------------------------------------------------------------------------
template<int BM, int BN, int BK, int WY, int WX, int GATED, int EPI, int CT, int SWZ>
__global__ __launch_bounds__(256)
void gemm_mfma(const unsigned short* __restrict__ A,
               const unsigned short* __restrict__ A2,
               const unsigned short* __restrict__ W,
               const float* __restrict__ bias,
               void* __restrict__ Cp, unsigned short* __restrict__ C2p,
               int K, int lda, int ldb, int ldc)
{
    constexpr int CPR = BK / 8;        // 16B chunks per LDS row
    constexpr int SWM = CPR - 1;
    constexpr int RPW = 64 / CPR;      // rows per wave per DMA pass
    constexpr int NPA = BM / (4 * RPW);
    constexpr int NPB = BN / (4 * RPW);
    constexpr int WGX = BN / (WX * 16);
    static_assert(WGX * (BM / (WY * 16)) == 4, "4 waves");
    __shared__ unsigned short As[BM * BK];
    __shared__ unsigned short Bs[BN * BK];

    const int tid  = threadIdx.x;
    const int lane = tid & 63;
    const int wave = tid >> 6;
    const int wx = wave % WGX, wy = wave / WGX;
    const int l15 = lane & 15, quad = lane >> 4;

    int bid = blockIdx.y * gridDim.x + blockIdx.x;
    if (SWZ) {
        const int nwg = gridDim.x * gridDim.y;
        if ((nwg & 7) == 0) {
            const int cpx = nwg >> 3;
            bid = (bid & 7) * cpx + (bid >> 3);
        }
    }
    const int bxi = bid % gridDim.x;
    const int byi = bid / gridDim.x;
    const long row0 = (long)byi * BM;
    const long col0 = (long)bxi * BN;

    // DMA lane mapping: lane -> (row-in-pass, swizzled source chunk)
    const int rin = lane / CPR;
    const int gc  = (lane % CPR) ^ (rin & SWM);

    f32x4 acc[WY][WX];
#pragma unroll
    for (int i = 0; i < WY; ++i)
#pragma unroll
        for (int j = 0; j < WX; ++j) acc[i][j] = (f32x4){0.f, 0.f, 0.f, 0.f};

    for (int k0 = 0; k0 < K; k0 += BK) {
        if (GATED == 0) {
#pragma unroll
            for (int p = 0; p < NPA; ++p) {
                const int rb = (p * 4 + wave) * RPW;
                const unsigned short* gp = A + (row0 + rb + rin) * (long)lda + k0 + gc * 8;
                const int lb = __builtin_amdgcn_readfirstlane(rb * BK);
                __builtin_amdgcn_global_load_lds(
                    (const __attribute__((address_space(1))) void*)gp,
                    (__attribute__((address_space(3))) void*)(As + lb), 16, 0, 0);
            }
        } else {
#pragma unroll
            for (int v = 0; v < BM * BK / 2048; ++v) {
                const int e = (v * 256 + tid) * 8;
                const int r = e / BK, c = (e % BK) / 8;
                const long off = (row0 + r) * (long)lda + k0 + c * 8;
                const us8 ta = *(const us8*)(A + off);
                const us8 tg = *(const us8*)(A2 + off);
                us8 t;
                t.a.x = f2us(us2f(ta.a.x) * silu_f(us2f(tg.a.x)));
                t.a.y = f2us(us2f(ta.a.y) * silu_f(us2f(tg.a.y)));
                t.a.z = f2us(us2f(ta.a.z) * silu_f(us2f(tg.a.z)));
                t.a.w = f2us(us2f(ta.a.w) * silu_f(us2f(tg.a.w)));
                t.b.x = f2us(us2f(ta.b.x) * silu_f(us2f(tg.b.x)));
                t.b.y = f2us(us2f(ta.b.y) * silu_f(us2f(tg.b.y)));
                t.b.z = f2us(us2f(ta.b.z) * silu_f(us2f(tg.b.z)));
                t.b.w = f2us(us2f(ta.b.w) * silu_f(us2f(tg.b.w)));
                *(us8*)&As[r * BK + ((c ^ (r & SWM)) * 8)] = t;
            }
        }
#pragma unroll
        for (int p = 0; p < NPB; ++p) {
            const int rb = (p * 4 + wave) * RPW;
            const unsigned short* gp = W + (col0 + rb + rin) * (long)ldb + k0 + gc * 8;
            const int lb = __builtin_amdgcn_readfirstlane(rb * BK);
            __builtin_amdgcn_global_load_lds(
                (const __attribute__((address_space(1))) void*)gp,
                (__attribute__((address_space(3))) void*)(Bs + lb), 16, 0, 0);
        }
        __syncthreads();   // drains vmcnt (DMA) + lgkmcnt before LDS reads

#pragma unroll
        for (int kk = 0; kk < BK / 32; ++kk) {
            bf16x8 aF[WY], bF[WX];
#pragma unroll
            for (int i = 0; i < WY; ++i) {
                const int r  = wy * WY * 16 + i * 16 + l15;
                const int kc = (kk * 4 + quad) ^ (r & SWM);
                aF[i] = *(const bf16x8*)&As[r * BK + kc * 8];
            }
#pragma unroll
            for (int j = 0; j < WX; ++j) {
                const int r  = wx * WX * 16 + j * 16 + l15;
                const int kc = (kk * 4 + quad) ^ (r & SWM);
                bF[j] = *(const bf16x8*)&Bs[r * BK + kc * 8];
            }
#pragma unroll
            for (int i = 0; i < WY; ++i)
#pragma unroll
                for (int j = 0; j < WX; ++j)
                    acc[i][j] = __builtin_amdgcn_mfma_f32_16x16x32_bf16(
                        aF[i], bF[j], acc[i][j], 0, 0, 0);
        }
        __syncthreads();
    }

    // ---- epilogue: lane holds rows quad*4+r, col l15 of each 16x16 tile ----
#pragma unroll
    for (int i = 0; i < WY; ++i)
#pragma unroll
        for (int j = 0; j < WX; ++j) {
            const long mb = row0 + wy * WY * 16 + i * 16 + quad * 4;
            const long n  = col0 + wx * WX * 16 + j * 16 + l15;
            const float bv = (EPI == 1) ? bias[n] : 0.0f;
#pragma unroll
            for (int r = 0; r < 4; ++r) {
                float val = acc[i][j][r];
                if (EPI == 1) val = softplus_f(val + bv);
                const long off = (mb + r) * (long)ldc + n;
                if (CT == 0) ((unsigned short*)Cp)[off] = f2us(val);
                else         ((float*)Cp)[off] = val;
                if (EPI == 2 && n < DT_RANK) C2p[(mb + r) * DT_RANK + n] = f2us(val);
            }
        }
}

// ---------------------------------------------------------------------------
// Depthwise causal conv1d (k=4) + bias + SiLU, 8 d-elements per thread.
// ---------------------------------------------------------------------------
__global__ __launch_bounds__(256)
void conv_silu8(const unsigned short* __restrict__ xz, const float* __restrict__ w,
                const float* __restrict__ bias, unsigned short* __restrict__ xb, int rev)
{
    const int idx = blockIdx.x * 256 + threadIdx.x;   // over M_ROWS * 128
    const int g = idx & 127;
    const int m = idx >> 7;
    const int b = m >> 12;
    const int t = m & (L_SEQ - 1);
    const int d = g * 8;

    float s[8];
    {
        const float4 b0 = *(const float4*)(bias + d);
        const float4 b1 = *(const float4*)(bias + d + 4);
        s[0] = b0.x; s[1] = b0.y; s[2] = b0.z; s[3] = b0.w;
        s[4] = b1.x; s[5] = b1.y; s[6] = b1.z; s[7] = b1.w;
    }
    float4 wv[8];
#pragma unroll
    for (int j = 0; j < 8; ++j) wv[j] = *(const float4*)(w + (d + j) * 4);

    const unsigned short* xbase = xz + (size_t)b * L_SEQ * 2048 + d;
#pragma unroll
    for (int k = 0; k < 4; ++k) {
        const int src = t - 3 + k;
        if (src >= 0) {
            const int sm = rev ? (L_SEQ - 1 - src) : src;
            const us8 xv = *(const us8*)(xbase + (size_t)sm * 2048);
            const float tap[8] = {us2f(xv.a.x), us2f(xv.a.y), us2f(xv.a.z), us2f(xv.a.w),
                                  us2f(xv.b.x), us2f(xv.b.y), us2f(xv.b.z), us2f(xv.b.w)};
#pragma unroll
            for (int j = 0; j < 8; ++j) {
                const float wk = (k == 0) ? wv[j].x : (k == 1) ? wv[j].y
                               : (k == 2) ? wv[j].z : wv[j].w;
                s[j] = fmaf(wk, tap[j], s[j]);
            }
        }
    }
    us8 o;
    o.a.x = f2us(silu_f(s[0])); o.a.y = f2us(silu_f(s[1]));
    o.a.z = f2us(silu_f(s[2])); o.a.w = f2us(silu_f(s[3]));
    o.b.x = f2us(silu_f(s[4])); o.b.y = f2us(silu_f(s[5]));
    o.b.z = f2us(silu_f(s[6])); o.b.w = f2us(silu_f(s[7]));
    *(us8*)(xb + (size_t)m * 1024 + d) = o;
}

// ---------------------------------------------------------------------------
// A-structure probe + power tree (verified rounds 2/6/17: absmax 7.6e-06).
// ---------------------------------------------------------------------------
__device__ __forceinline__ bool a_struct_fast(const float* __restrict__ Alog,
                                              int d, float& A0)
{
    A0 = -__expf(Alog[d * 16]);
    bool fast = true;
#pragma unroll
    for (int n = 1; n < 16; ++n) {
        const float an = -__expf(Alog[d * 16 + n]);
        const float tg = (float)(n + 1) * A0;
        fast = fast && (fabsf(an - tg) <= 1e-5f * fabsf(tg));
    }
    return fast;
}
__device__ __forceinline__ void pow_tree16(float e1, float w[16])
{
    w[0] = e1;
    w[1] = w[0] * w[0];  w[2] = w[1] * w[0];  w[3] = w[1] * w[1];
    w[4] = w[3] * w[0];  w[5] = w[3] * w[1];  w[6] = w[3] * w[2];  w[7] = w[3] * w[3];
#pragma unroll
    for (int n = 8; n < 16; ++n) w[n] = w[7] * w[n - 8];
}

// ---------------------------------------------------------------------------
// Chunked selective scan, phase A. ROUND-6 STRUCTURE (1024 thr, grid (NC,B)).
// Session lessons: (a) block-split = occupancy no-op (total-thread cap);
// (b) lane-pair n-split -> 4x HBM traffic (half-wave 2B stores), 2.4x slower;
// (c) float4 LDS reads = NULL (LDS not the binder; round 17).
// This round: VALUBusy 59% is the binder -> pack the dominant h-update
// f32 math into f32x2 (CDNA v_pk_fma_f32, VOP3P) to halve those VALU ops.
// h chains are element-independent -> bit-identical; only y's summation
// order changes (even/odd pair-sum + horizontal add).
// ---------------------------------------------------------------------------
__global__ __launch_bounds__(1024)
void scan_a(const unsigned short* __restrict__ dtq, const unsigned short* __restrict__ xq,
            const float* __restrict__ dbl, const float* __restrict__ Alog,
            float* __restrict__ hF, float* __restrict__ Ssum)
{
    const int d = threadIdx.x;
    const int c = blockIdx.x;
    const int b = blockIdx.y;

    __shared__ float Bsh[CHK][16];
    {
        const int tl = d >> 4, nl = d & 15;
        Bsh[tl][nl] = dbl[((size_t)b * L_SEQ + c * CHK + tl) * 64 + DT_RANK + nl];
    }
    __syncthreads();

    float A0;
    const bool fast = a_struct_fast(Alog, d, A0);

    const size_t base = ((size_t)b * L_SEQ + c * CHK) * 1024 + d;
    const unsigned short* dtp = dtq + base;
    const unsigned short* xp  = xq + base;
    float S = 0.0f;

    if (fast) {
        f32x2 h2[8];
#pragma unroll
        for (int k = 0; k < 8; ++k) h2[k] = (f32x2){0.f, 0.f};
        unsigned short bd[4], bx[4];
#pragma unroll
        for (int i = 0; i < 4; ++i) {
            bd[i] = dtp[(size_t)i * 1024];
            bx[i] = xp[(size_t)i * 1024];
        }
        for (int t0 = 0; t0 < CHK; t0 += 4) {
            unsigned short nd[4], nx[4];
            const bool pf = (t0 + 4 < CHK);
            if (pf) {
#pragma unroll
                for (int i = 0; i < 4; ++i) {
                    nd[i] = dtp[(size_t)(t0 + 4 + i) * 1024];
                    nx[i] = xp[(size_t)(t0 + 4 + i) * 1024];
                }
            }
#pragma unroll
            for (int i = 0; i < 4; ++i) {
                const float dt = us2f(bd[i]);
                const float xv = us2f(bx[i]);
                S += dt;
                const float dtx = dt * xv;
                float w[16];
                pow_tree16(__expf(dt * A0), w);
                const f32x2* bv2 = (const f32x2*)&Bsh[t0 + i][0];
                const f32x2 dtx2 = (f32x2){dtx, dtx};
#pragma unroll
                for (int k = 0; k < 8; ++k) {
                    const f32x2 w2 = (f32x2){w[2 * k], w[2 * k + 1]};
                    h2[k] = w2 * h2[k] + dtx2 * bv2[k];
                }
            }
            if (pf) {
#pragma unroll
                for (int i = 0; i < 4; ++i) { bd[i] = nd[i]; bx[i] = nx[i]; }
            }
        }
        f32x2* hp2 = (f32x2*)(hF + (((size_t)(b * NC + c) * 1024 + d) << 4));
#pragma unroll
        for (int k = 0; k < 8; ++k) hp2[k] = h2[k];
    } else {
        float h[16];
#pragma unroll
        for (int n = 0; n < 16; ++n) h[n] = 0.0f;
        float Acoef[16];
#pragma unroll
        for (int n = 0; n < 16; ++n) Acoef[n] = -__expf(Alog[d * 16 + n]);
        unsigned short vd = dtp[0], vx = xp[0];
        for (int t = 0; t < CHK; ++t) {
            unsigned short vd2 = 0, vx2 = 0;
            if (t + 1 < CHK) {
                vd2 = dtp[(size_t)(t + 1) * 1024];
                vx2 = xp[(size_t)(t + 1) * 1024];
            }
            const float dt = us2f(vd);
            const float xv = us2f(vx);
            S += dt;
            const float dtx = dt * xv;
#pragma unroll
            for (int n = 0; n < 16; ++n)
                h[n] = fmaf(__expf(dt * Acoef[n]), h[n], dtx * Bsh[t][n]);
            vd = vd2; vx = vx2;
        }
        float* hp = hF + (((size_t)(b * NC + c) * 1024 + d) << 4);
#pragma unroll
        for (int n = 0; n < 16; ++n) hp[n] = h[n];
    }

    Ssum[(size_t)(b * NC + c) * 1024 + d] = S;
}

// ---------------------------------------------------------------------------
// Phase B: sequential combine over chunks.
// ---------------------------------------------------------------------------
__global__ __launch_bounds__(256)
void scan_b(float* __restrict__ hF, const float* __restrict__ Ssum,
            const float* __restrict__ Alog)
{
    const int idx = blockIdx.x * 256 + threadIdx.x;   // B*D*16
    const int n  = idx & 15;
    const int dn = idx >> 4;
    const int d  = dn & (D_INNER - 1);
    const int b  = dn >> 10;

    const float Acoef = -__expf(Alog[d * 16 + n]);
    float H = 0.0f;
    for (int c = 0; c < NC; ++c) {
        const size_t base = (size_t)(b * NC + c) * 1024 + d;
        const float S = Ssum[base];
        float* hp = hF + (base << 4) + n;
        const float hOld = *hp;
        *hp = H;
        H = fmaf(__expf(Acoef * S), H, hOld);
    }
}

// ---------------------------------------------------------------------------
// Phase C: re-run chunk from true h_init; fused D*x + silu(z) gate; rev maps
// back to original time order; acc=1 accumulates (branch r into yfr).
// gate!=nullptr (branch r): final output = (yfr_old + y_r) * silu(gate[oi]).
// ROUND-6 STRUCTURE + packed f32x2 h/y math (see scan_a note).
// ---------------------------------------------------------------------------
__global__ __launch_bounds__(1024)
void scan_c(const unsigned short* __restrict__ dtq, const unsigned short* __restrict__ xq,
            const float* __restrict__ dbl, const float* __restrict__ hF,
            const float* __restrict__ Alog, const float* __restrict__ Dp,
            const unsigned short* __restrict__ xz, unsigned short* __restrict__ yout,
            const unsigned short* __restrict__ gate, int rev, int acc)
{
    const int d = threadIdx.x;
    const int c = blockIdx.x;
    const int b = blockIdx.y;

    __shared__ float Bsh[CHK][16];
    __shared__ float Csh[CHK][16];
    {
        const int tl = d >> 4, nl = d & 15;
        const size_t rb = ((size_t)b * L_SEQ + c * CHK + tl) * 64;
        Bsh[tl][nl] = dbl[rb + DT_RANK + nl];
        Csh[tl][nl] = dbl[rb + DT_RANK + D_STATE + nl];
    }
    __syncthreads();

    float A0;
    const bool fast = a_struct_fast(Alog, d, A0);
    const float Dd = Dp[d];

    const size_t base = ((size_t)b * L_SEQ + c * CHK) * 1024 + d;
    const unsigned short* dtp = dtq + base;
    const unsigned short* xp  = xq + base;
    const unsigned short* z_base = xz + (size_t)b * L_SEQ * 2048 + D_INNER + d;
    const unsigned short* g_base = gate ? gate + (size_t)b * L_SEQ * D_INNER + d : nullptr;
    unsigned short* y_base = yout + (size_t)b * L_SEQ * D_INNER + d;

    if (fast) {
        f32x2 h2[8];
        {
            const f32x2* hp2 = (const f32x2*)(hF + (((size_t)(b * NC + c) * 1024 + d) << 4));
#pragma unroll
            for (int k = 0; k < 8; ++k) h2[k] = hp2[k];
        }
        unsigned short bd[4], bx[4], bz[4], bg[4];
#pragma unroll
        for (int i = 0; i < 4; ++i) {
            bd[i] = dtp[(size_t)i * 1024];
            bx[i] = xp[(size_t)i * 1024];
            const int tg = c * CHK + i;
            const int tm = rev ? (L_SEQ - 1 - tg) : tg;
            bz[i] = z_base[(size_t)tm * 2048];
            bg[i] = g_base ? g_base[(size_t)tm * D_INNER] : (unsigned short)0;
        }
        for (int t0 = 0; t0 < CHK; t0 += 4) {
            unsigned short nd[4], nx[4], nz[4], ng[4];
            const bool pf = (t0 + 4 < CHK);
            if (pf) {
#pragma unroll
                for (int i = 0; i < 4; ++i) {
                    nd[i] = dtp[(size_t)(t0 + 4 + i) * 1024];
                    nx[i] = xp[(size_t)(t0 + 4 + i) * 1024];
                    const int tg = c * CHK + t0 + 4 + i;
                    const int tm = rev ? (L_SEQ - 1 - tg) : tg;
                    nz[i] = z_base[(size_t)tm * 2048];
                    ng[i] = g_base ? g_base[(size_t)tm * D_INNER] : (unsigned short)0;
                }
            }
#pragma unroll
            for (int i = 0; i < 4; ++i) {
                const float dt = us2f(bd[i]);
                const float xv = us2f(bx[i]);
                const float dtx = dt * xv;
                float w[16];
                pow_tree16(__expf(dt * A0), w);
                const f32x2* bv2 = (const f32x2*)&Bsh[t0 + i][0];
                const f32x2* cv2 = (const f32x2*)&Csh[t0 + i][0];
                const f32x2 dtx2 = (f32x2){dtx, dtx};
                f32x2 y2 = (f32x2){0.f, 0.f};
#pragma unroll
                for (int k = 0; k < 8; ++k) {
                    const f32x2 w2 = (f32x2){w[2 * k], w[2 * k + 1]};
                    h2[k] = w2 * h2[k] + dtx2 * bv2[k];
                    y2 = h2[k] * cv2[k] + y2;
                }
                const float y = y2.x + y2.y;
                const int tg = c * CHK + t0 + i;
                const int tm = rev ? (L_SEQ - 1 - tg) : tg;
                const float z = us2f(bz[i]);
                float yo = (y + Dd * xv) * silu_f(z);
                const size_t oi = (size_t)tm * D_INNER;
                if (acc) yo += us2f(y_base[oi]);
                if (g_base) yo *= silu_f(us2f(bg[i]));
                y_base[oi] = f2us(yo);
            }
            if (pf) {
#pragma unroll
                for (int i = 0; i < 4; ++i) { bd[i] = nd[i]; bx[i] = nx[i]; bz[i] = nz[i]; bg[i] = ng[i]; }
            }
        }
    } else {
        float h[16];
        {
            const float* hp = hF + (((size_t)(b * NC + c) * 1024 + d) << 4);
#pragma unroll
            for (int n = 0; n < 16; ++n) h[n] = hp[n];
        }
        float Acoef[16];
#pragma unroll
        for (int n = 0; n < 16; ++n) Acoef[n] = -__expf(Alog[d * 16 + n]);
        unsigned short vd = dtp[0], vx = xp[0];
        for (int t = 0; t < CHK; ++t) {
            unsigned short vd2 = 0, vx2 = 0;
            if (t + 1 < CHK) {
                vd2 = dtp[(size_t)(t + 1) * 1024];
                vx2 = xp[(size_t)(t + 1) * 1024];
            }
            const float dt = us2f(vd);
            const float xv = us2f(vx);
            const float dtx = dt * xv;
            float y = 0.0f;
#pragma unroll
            for (int n = 0; n < 16; ++n) {
                h[n] = fmaf(__expf(dt * Acoef[n]), h[n], dtx * Bsh[t][n]);
                y = fmaf(h[n], Csh[t][n], y);
            }
            const int tg = c * CHK + t;
            const int tm = rev ? (L_SEQ - 1 - tg) : tg;
            const float z = us2f(z_base[(size_t)tm * 2048]);
            float yo = (y + Dd * xv) * silu_f(z);
            const size_t oi = (size_t)tm * D_INNER;
            if (acc) yo += us2f(y_base[oi]);
            if (g_base) yo *= silu_f(us2f(g_base[oi]));
            y_base[oi] = f2us(yo);
            vd = vd2; vx = vx2;
        }
    }
}

// ---------------------------------------------------------------------------
extern "C" void kernel_launch(void* const* d_in, const int* in_sizes, int n_in,
                              void* d_out, int out_size, void* d_ws, size_t ws_size,
                              hipStream_t stream)
{
    const float* hs    = (const float*)d_in[0];
    const float* ahs   = (const float*)d_in[1];
    const float* in_w  = (const float*)d_in[2];
    const float* in_gw = (const float*)d_in[3];
    const float* convw[3] = {(const float*)d_in[4], (const float*)d_in[6], (const float*)d_in[8]};
    const float* convb[3] = {(const float*)d_in[5], (const float*)d_in[7], (const float*)d_in[9]};
    const float* xproj[3] = {(const float*)d_in[10], (const float*)d_in[11], (const float*)d_in[12]};
    const float* dtw[3]   = {(const float*)d_in[13], (const float*)d_in[15], (const float*)d_in[17]};
    const float* dtbias[3]= {(const float*)d_in[14], (const float*)d_in[16], (const float*)d_in[18]};
    const float* Alog[3]  = {(const float*)d_in[19], (const float*)d_in[20], (const float*)d_in[21]};
    const float* Dp[3]    = {(const float*)d_in[22], (const float*)d_in[23], (const float*)d_in[24]};
    const float* out_w = (const float*)d_in[25];

    // Workspace (~228 MB, matches round-7 proven size):
    unsigned short* regA = (unsigned short*)d_ws;                    // M*2048 (axz then xz)
    float* dbl  = (float*)(regA + (size_t)M_ROWS * 2048);            // M*64 f32
    unsigned short* xb  = (unsigned short*)(dbl + (size_t)M_ROWS * 64); // M*1024
    unsigned short* dtv = xb  + (size_t)M_ROWS * 1024;               // M*1024
    unsigned short* yfr = dtv + (size_t)M_ROWS * 1024;               // M*1024 (first half = inb)
    unsigned short* yg  = yfr + (size_t)M_ROWS * 1024;               // M*1024
    float* hF   = (float*)(yg + (size_t)M_ROWS * 1024);              // B*NC*1024*16 f32
    float* Ssum = hF + (size_t)B_SZ * NC * 1024 * 16;                // B*NC*1024 f32
    unsigned short* dtin = (unsigned short*)(Ssum + (size_t)B_SZ * NC * 1024); // M*32
    unsigned short* wbig = dtin + (size_t)M_ROWS * 32;               // 2048*512
    unsigned short* wout = wbig + (size_t)2048 * 512;                // 512*1024
    unsigned short* wxpb = wout + (size_t)512 * 1024;                // 3 x 64*1024
    unsigned short* wdtb = wxpb + (size_t)3 * 64 * 1024;             // 3 x 1024*32
    unsigned short* inb  = yfr;   // 16 MB staging for bf16(ahs)/bf16(hs)

    const dim3 blk(256);

    // ---- cvt1: ahs + in_gw + out_w + xproj x3 + dtw x3 (one dispatch) ----
    {
        CvtArgs a;
        unsigned int acc = 0;
        const float* srcs[9] = {ahs, in_gw, out_w, xproj[0], xproj[1], xproj[2],
                                dtw[0], dtw[1], dtw[2]};
        unsigned short* dsts[9] = {inb, wbig, wout,
                                   wxpb, wxpb + 64 * 1024, wxpb + 2 * 64 * 1024,
                                   wdtb, wdtb + 1024 * 32, wdtb + 2 * 1024 * 32};
        const unsigned int sz[9] = {M_ROWS * 512u, 2048u * 512u, 512u * 1024u,
                                    64u * 1024u, 64u * 1024u, 64u * 1024u,
                                    1024u * 32u, 1024u * 32u, 1024u * 32u};
        for (int i = 0; i < 9; ++i) {
            a.src[i] = srcs[i]; a.dst[i] = dsts[i];
            acc += sz[i] / 4; a.vend[i] = acc;
        }
        a.nseg = 9;
        cvt_multi<<<dim3((acc + 255) / 256), blk, 0, stream>>>(a);
    }

    const int order[3] = {2, 0, 1};   // g, f, r

    // axz = bf16(ahs) @ in_proj_g^T -> regA   (SWZ=1: A re-read x16, L2 win)
    gemm_mfma<128,128,64,4,4,0,0,0,1><<<dim3(16, 128), blk, 0, stream>>>(
        inb, nullptr, wbig, nullptr, regA, nullptr, D_MODEL, D_MODEL, D_MODEL, 2048);

    for (int oi = 0; oi < 3; ++oi) {
        const int br = order[oi];
        const int rev  = (br == 1) ? 1 : 0;
        const int accf = (br == 1) ? 1 : 0;
        unsigned short* ybuf = (br == 2) ? yg : yfr;
        const unsigned short* gatep = (br == 1) ? yg : nullptr;

        if (br == 0) {
            // cvt2: hs + in_w into the (now free) inb/wbig buffers
            CvtArgs a;
            a.src[0] = hs;   a.dst[0] = inb;  a.vend[0] = M_ROWS * 512u / 4;
            a.src[1] = in_w; a.dst[1] = wbig; a.vend[1] = a.vend[0] + 2048u * 512u / 4;
            a.nseg = 2;
            cvt_multi<<<dim3((a.vend[1] + 255) / 256), blk, 0, stream>>>(a);
            gemm_mfma<128,128,64,4,4,0,0,0,1><<<dim3(16, 128), blk, 0, stream>>>(
                inb, nullptr, wbig, nullptr, regA, nullptr, D_MODEL, D_MODEL, D_MODEL, 2048);
        }

        conv_silu8<<<dim3(M_ROWS * 128 / 256), blk, 0, stream>>>(
            regA, convw[br], convb[br], xb, rev);

        // dbl = xb @ xproj^T (f32) + dual-write bf16 dtin (cols<32)  [SWZ=0]
        gemm_mfma<64,64,64,2,2,0,2,1,0><<<dim3(1, 256), blk, 0, stream>>>(
            xb, nullptr, wxpb + br * 64 * 1024, nullptr, dbl, dtin,
            D_INNER, D_INNER, D_INNER, 64);

        // dtv = softplus(dtin @ dtw^T + dtb), bf16 contiguous  [SWZ=0 --
        // round-5: blanket swizzle tripled this dispatch, 167.9us]
        gemm_mfma<128,128,32,4,4,0,1,0,0><<<dim3(8, 128), blk, 0, stream>>>(
            dtin, nullptr, wdtb + br * 1024 * 32, dtbias[br], dtv, nullptr,
            DT_RANK, DT_RANK, DT_RANK, D_INNER);

        scan_a<<<dim3(NC, B_SZ), dim3(1024), 0, stream>>>(dtv, xb, dbl, Alog[br], hF, Ssum);
        scan_b<<<dim3((B_SZ * D_INNER * 16) / 256), blk, 0, stream>>>(hF, Ssum, Alog[br]);
        scan_c<<<dim3(NC, B_SZ), dim3(1024), 0, stream>>>(
            dtv, xb, dbl, hF, Alog[br], Dp[br], regA, ybuf, gatep, rev, accf);
    }

    // out = ygated @ out_proj^T (plain DMA-staged GEMM; gate fused into
    // branch-r scan_c)  [SWZ=0]
    gemm_mfma<128,128,64,4,4,0,0,1,0><<<dim3(4, 128), blk, 0, stream>>>(
        yfr, nullptr, wout, nullptr, d_out, nullptr, D_INNER, D_INNER, D_INNER, D_MODEL);
}